// Round 6
// baseline (11445.740 us; speedup 1.0000x reference)
//
#include <hip/hip_runtime.h>
#include <math.h>

#define BB 64
#define TT 512
#define EE 256
#define MACRO 10
#define NT 512

typedef unsigned short u16;
typedef unsigned int u32;
typedef u16 us4 __attribute__((ext_vector_type(4)));
typedef _Float16 h2 __attribute__((ext_vector_type(2)));

// ---- ws layout in u32 words ----
// 4 weight shards (one per head/member), packed:
//   per shard: Wq[128][64] | Wk | Wv | Wo[32][256] | W1[128][256] | W2[128][256]
#define SH_STRIDE 98304
#define SH_WK 8192
#define SH_WV 16384
#define SH_WO 24576
#define SH_W1 32768
#define SH_W2 65536
#define W_WI  393216   // Wi pairs [32][256] = 8192 words (replicated use)
#define W_WA  401408   // Wa f16 pairs, 131072 words
#define W_PY  532480   // partial_y  [64][4][256] f32
#define W_PXO 598016   // partial_xo [64][4][256] f32
#define W_SEQ 663552   // seqy[256] | seqx[256]
#define W_XO  664064   // xout f16 pairs, 4194304 words
#define CONV_TOTAL 664064

__device__ __forceinline__ u32 pack2(float a, float b) {
  union { _Float16 h; u16 s; } ca, cb;
  ca.h = (_Float16)a; cb.h = (_Float16)b;
  return (u32)ca.s | ((u32)cb.s << 16);
}
__device__ __forceinline__ float h2f(u16 s) {
  union { u16 s; _Float16 h; } c; c.s = s; return (float)c.h;
}
__device__ __forceinline__ float dot2(u32 x, u32 w, float c) {
#if __has_builtin(__builtin_amdgcn_fdot2)
  return __builtin_amdgcn_fdot2(__builtin_bit_cast(h2, x), __builtin_bit_cast(h2, w), c, false);
#else
  union { u32 u; _Float16 h[2]; } a, b; a.u = x; b.u = w;
  return c + (float)a.h[0] * (float)b.h[0] + (float)a.h[1] * (float)b.h[1];
#endif
}
__device__ __forceinline__ float gelu_f(float x) {
  float x3 = x * x * x;
  float u = 0.7978845608028654f * (x + 0.044715f * x3);
  return 0.5f * x * (1.0f + tanhf(u));
}

__global__ __launch_bounds__(256) void convert_kernel(
    const float* __restrict__ Wi, const float* __restrict__ Wq, const float* __restrict__ Wk,
    const float* __restrict__ Wv, const float* __restrict__ Wo, const float* __restrict__ W1,
    const float* __restrict__ W2, const float* __restrict__ Wa, u16* __restrict__ ws) {
  u32* ws32 = (u32*)ws;
  for (int i = blockIdx.x * blockDim.x + threadIdx.x; i < CONV_TOTAL;
       i += gridDim.x * blockDim.x) {
    if (i < 393216) {
      int j = i / SH_STRIDE, off = i - j * SH_STRIDE;
      float a, b;
      if (off < SH_WO) {
        int which = off >> 13, r = off & 8191, k2 = r >> 6, n = r & 63;
        const float* W = which == 0 ? Wq : (which == 1 ? Wk : Wv);
        a = W[(2 * k2) * 256 + j * 64 + n];
        b = W[(2 * k2 + 1) * 256 + j * 64 + n];
      } else if (off < SH_W1) {
        int r = off - SH_WO, k2 = r >> 8, n = r & 255;
        a = Wo[j * 16384 + (2 * k2) * 256 + n];
        b = Wo[j * 16384 + (2 * k2 + 1) * 256 + n];
      } else if (off < SH_W2) {
        int r = off - SH_W1, k2 = r >> 8, n = r & 255;
        a = W1[(2 * k2) * 1024 + j * 256 + n];
        b = W1[(2 * k2 + 1) * 1024 + j * 256 + n];
      } else {
        int r = off - SH_W2, k2 = r >> 8, n = r & 255;
        a = W2[(j * 256 + 2 * k2) * 256 + n];
        b = W2[(j * 256 + 2 * k2 + 1) * 256 + n];
      }
      ws32[i] = pack2(a, b);
    } else if (i < W_WA) {
      int w = i - W_WI, k2 = w >> 8, n = w & 255;
      ws32[i] = pack2(Wi[(2 * k2) * 256 + n], Wi[(2 * k2 + 1) * 256 + n]);
    } else if (i < W_PY) {
      int w = i - W_WA;
      ws32[i] = pack2(Wa[2 * w], Wa[2 * w + 1]);
    } else {
      ws32[i] = 0;  // zero partials + seq counters
    }
  }
}

// reg-weight matvec: thread (s,g) owns CK2 k2-words x CN cols; partials to LDS
template <int G, int CN, int CK2, int N>
__device__ __forceinline__ void mvr(const u32* __restrict__ w, const u32* __restrict__ x16,
                                    float* __restrict__ part, int tid) {
  const int g = tid & (G - 1);
  const int s = tid / G;
  float acc[CN];
#pragma unroll
  for (int n = 0; n < CN; ++n) acc[n] = 0.f;
#pragma unroll
  for (int jj = 0; jj < CK2; ++jj) {
    u32 xp = x16[s * CK2 + jj];
#pragma unroll
    for (int n = 0; n < CN; ++n) acc[n] = dot2(xp, w[jj * CN + n], acc[n]);
  }
  float* pp = part + s * N + g * CN;
#pragma unroll
  for (int n = 0; n < CN; ++n) pp[n] = acc[n];
}

// __launch_bounds__(512, 2): 2 waves/EU -> 256-VGPR budget. Without the 2nd arg the
// compiler budgeted 128 VGPRs (2 blocks/CU) and spilled the 176 resident weight
// words to scratch (R5: VGPR_Count=128, spill reloads L2-resident, 22us/step).
__global__ __launch_bounds__(NT, 2) void scan_kernel(
    const float* __restrict__ obs, const unsigned char* __restrict__ freeze,
    const float* __restrict__ bi, const float* __restrict__ temb,
    const float* __restrict__ alpha, const float* __restrict__ lam,
    const float* __restrict__ ln1s, const float* __restrict__ ln1b,
    const float* __restrict__ bq, const float* __restrict__ bk,
    const float* __restrict__ bv, const float* __restrict__ bo,
    const float* __restrict__ ln2s, const float* __restrict__ ln2b,
    const float* __restrict__ b1, const float* __restrict__ b2,
    u16* __restrict__ wsw) {
  __shared__ u32  s_w2[16384];         // 64 KB: W2 rows j2=8..15
  __shared__ float s_part[3072];       // 12 KB partials
  __shared__ float s_kc[64 * 16];      // k cache [d][slot]
  __shared__ float s_vc[16 * 64];      // v cache [slot][d]
  __shared__ float s_temb[MACRO * EE]; // 10 KB
  __shared__ u32  s_xin16[128], s_y16[128], s_z16[128], s_h16[128];
  __shared__ u32  s_ctx16[32], s_obs16[32];
  __shared__ float s_q[64], s_attn[16], s_red[16];
  __shared__ u32  s_frz[TT / 4];

  const int blk = blockIdx.x;
  const int b = blk & 63;
  const int j = blk >> 6;  // member = head = shard
  const int tid = threadIdx.x;
  u32* W32 = (u32*)wsw;
  const u32* shard = W32 + j * SH_STRIDE;
  float* py  = (float*)(W32 + W_PY);
  float* pxo = (float*)(W32 + W_PXO);
  int* seqy = (int*)(W32 + W_SEQ);
  int* seqx = seqy + 256;
  u32* xog = W32 + W_XO;

  // ---- resident weights in registers (f16 pair-words, static indexing) ----
  u32 wWi[16], wQ[16], wK[16], wV[16], wWo[16], wW1[64], wW2r[32];
  {
    const int g = tid & 63, s = tid >> 6;
#pragma unroll
    for (int i = 0; i < 16; ++i)
      wWi[i] = W32[W_WI + (s * 4 + (i >> 2)) * 256 + g * 4 + (i & 3)];
#pragma unroll
    for (int i = 0; i < 16; ++i)
      wWo[i] = shard[SH_WO + (s * 4 + (i >> 2)) * 256 + g * 4 + (i & 3)];
#pragma unroll
    for (int i = 0; i < 64; ++i)
      wW1[i] = shard[SH_W1 + (s * 16 + (i >> 2)) * 256 + g * 4 + (i & 3)];
#pragma unroll
    for (int i = 0; i < 32; ++i)
      wW2r[i] = shard[SH_W2 + (s * 16 + (i >> 2)) * 256 + g * 4 + (i & 3)];
  }
  {
    const int g = tid & 31, s = tid >> 5;
#pragma unroll
    for (int i = 0; i < 16; ++i) {
      wQ[i] = shard[(s * 8 + (i >> 1)) * 64 + g * 2 + (i & 1)];
      wK[i] = shard[SH_WK + (s * 8 + (i >> 1)) * 64 + g * 2 + (i & 1)];
      wV[i] = shard[SH_WV + (s * 8 + (i >> 1)) * 64 + g * 2 + (i & 1)];
    }
  }
  // W2 rows 8..15 of each slice -> LDS
  for (int i = tid; i < 16384; i += NT)
    s_w2[i] = shard[SH_W2 + ((i >> 11) * 16 + 8 + ((i >> 8) & 7)) * 256 + (i & 255)];

  // ---- per-thread params ----
  float bi_r = 0, a_r = 0, l_r = 0, p1s_r = 0, p1b_r = 0, p2s_r = 0, p2b_r = 0;
  float bo_r = 0, b1_r = 0, b2_r = 0, bqkv_r = 0, ssum_r = 0;
  if (tid < 256) {
    bi_r = bi[tid];
    a_r = 1.f / (1.f + expf(-alpha[tid]));
    l_r = 1.f / (1.f + expf(-lam[tid]));
    p1s_r = ln1s[tid]; p1b_r = ln1b[tid];
    p2s_r = ln2s[tid]; p2b_r = ln2b[tid];
    b1_r = b1[j * 256 + tid]; b2_r = b2[tid];
    if (j == 0) bo_r = bo[tid];
  }
  if (tid < 192) {
    int r = tid >> 6, c = tid & 63;
    bqkv_r = (r == 0 ? bq : (r == 1 ? bk : bv))[j * 64 + c];
  }
  for (int i = tid; i < MACRO * EE; i += NT) s_temb[i] = temb[i];
  if (tid < TT / 4) s_frz[tid] = ((const u32*)(freeze + (size_t)b * TT))[tid];
  // empty mem: k = bk, v = bv
  for (int i = tid; i < 1024; i += NT) {
    s_kc[i] = bk[j * 64 + (i >> 4)];
    s_vc[i] = bv[j * 64 + (i & 63)];
  }
  float4 obs_pf = make_float4(0.f, 0.f, 0.f, 0.f);
  if (tid < 16) obs_pf = *(const float4*)(obs + (size_t)b * TT * 64 + tid * 4);
  __syncthreads();

  for (int t = 0; t < TT; ++t) {
    const int tmod = t % MACRO;
    const int slot = t & 15;
    if (tid < 16) {
      s_obs16[tid * 2]     = pack2(obs_pf.x, obs_pf.y);
      s_obs16[tid * 2 + 1] = pack2(obs_pf.z, obs_pf.w);
    }
    __syncthreads();

    // x_in = obs @ Wi + bi + temb + ssum*a   (Wi replicated: identical on all members)
    mvr<64, 4, 4, 256>(wWi, s_obs16, s_part, tid);
    if (tid < 16) {
      int tn = (t + 1 < TT) ? t + 1 : t;
      obs_pf = *(const float4*)(obs + ((size_t)b * TT + tn) * 64 + tid * 4);
    }
    __syncthreads();
    float xin_r = 0.f;
    {
      float x = 0.f;
      if (tid < 256) {
        float v = 0.f;
#pragma unroll
        for (int s = 0; s < 8; ++s) v += s_part[s * 256 + tid];
        xin_r = v + bi_r + s_temb[tmod * 256 + tid] + ssum_r * a_r;
        float vn = __shfl_xor(xin_r, 1);
        if (!(tid & 1)) s_xin16[tid >> 1] = pack2(xin_r, vn);
        x = xin_r;
      }
      // LN1 -> y16
      float s1 = x, s2 = x * x;
#pragma unroll
      for (int o = 32; o >= 1; o >>= 1) { s1 += __shfl_xor(s1, o, 64); s2 += __shfl_xor(s2, o, 64); }
      if (tid < 256 && (tid & 63) == 0) { s_red[tid >> 6] = s1; s_red[8 + (tid >> 6)] = s2; }
      __syncthreads();
      if (tid < 256) {
        float S1 = s_red[0] + s_red[1] + s_red[2] + s_red[3];
        float S2 = s_red[8] + s_red[9] + s_red[10] + s_red[11];
        float m = S1 * (1.f / 256), rs = rsqrtf(S2 * (1.f / 256) - m * m + 1e-6f);
        float v = (x - m) * rs * p1s_r + p1b_r;
        float vn = __shfl_xor(v, 1);
        if (!(tid & 1)) s_y16[tid >> 1] = pack2(v, vn);
      }
    }
    __syncthreads();

    // q/k/v (head j only)
    mvr<32, 2, 8, 64>(wQ, s_y16,   s_part,        tid);
    mvr<32, 2, 8, 64>(wK, s_xin16, s_part + 1024, tid);
    mvr<32, 2, 8, 64>(wV, s_xin16, s_part + 2048, tid);
    __syncthreads();
    if (tid < 192) {
      int r = tid >> 6, c = tid & 63;
      float v = 0.f;
#pragma unroll
      for (int s = 0; s < 16; ++s) v += s_part[r * 1024 + s * 64 + c];
      v += bqkv_r;
      if (r == 0)      s_q[c] = v * 0.125f;
      else if (r == 1) s_kc[c * 16 + slot] = v;
      else             s_vc[slot * 64 + c] = v;
    }
    __syncthreads();

    // attention (local head): scores -> softmax -> ctx
    if (tid < 16) {
      int sl = (t + 1 + tid) & 15;
      float sc = 0.f;
#pragma unroll
      for (int d = 0; d < 64; ++d) sc += s_q[d] * s_kc[d * 16 + sl];
      float mx = sc;
#pragma unroll
      for (int o = 8; o >= 1; o >>= 1) mx = fmaxf(mx, __shfl_xor(mx, o, 16));
      float ex = expf(sc - mx), sm = ex;
#pragma unroll
      for (int o = 8; o >= 1; o >>= 1) sm += __shfl_xor(sm, o, 16);
      s_attn[tid] = ex / sm;
    }
    __syncthreads();
    if (tid < 64) {
      float sum = 0.f;
#pragma unroll
      for (int m = 0; m < 16; ++m) {
        int sl = (t + 1 + m) & 15;
        sum += s_attn[m] * s_vc[sl * 64 + tid];
      }
      float vn = __shfl_xor(sum, 1);
      if (!(tid & 1)) s_ctx16[tid >> 1] = pack2(sum, vn);
    }
    __syncthreads();

    // y partial = ctx_j @ Wo[j] (+bo on j0) -> post & all-reduce
    mvr<64, 4, 4, 256>(wWo, s_ctx16, s_part, tid);
    __syncthreads();
    if (tid < 256) {
      float v = 0.f;
#pragma unroll
      for (int s = 0; s < 8; ++s) v += s_part[s * 256 + tid];
      if (j == 0) v += bo_r;
      __hip_atomic_store(&py[(b * 4 + j) * 256 + tid], v, __ATOMIC_RELAXED, __HIP_MEMORY_SCOPE_AGENT);
    }
    __syncthreads();
    if (tid == 0) {
      __threadfence();
      __hip_atomic_store(&seqy[b * 4 + j], t + 1, __ATOMIC_RELEASE, __HIP_MEMORY_SCOPE_AGENT);
    }
    if (tid < 4) {
      while (__hip_atomic_load(&seqy[b * 4 + tid], __ATOMIC_ACQUIRE, __HIP_MEMORY_SCOPE_AGENT) < t + 1)
        __builtin_amdgcn_s_sleep(1);
    }
    __syncthreads();
    float xm_r = 0.f;
    {
      float x = 0.f;
      if (tid < 256) {
        float y0 = __hip_atomic_load(&py[(b * 4 + 0) * 256 + tid], __ATOMIC_RELAXED, __HIP_MEMORY_SCOPE_AGENT);
        float y1 = __hip_atomic_load(&py[(b * 4 + 1) * 256 + tid], __ATOMIC_RELAXED, __HIP_MEMORY_SCOPE_AGENT);
        float y2 = __hip_atomic_load(&py[(b * 4 + 2) * 256 + tid], __ATOMIC_RELAXED, __HIP_MEMORY_SCOPE_AGENT);
        float y3 = __hip_atomic_load(&py[(b * 4 + 3) * 256 + tid], __ATOMIC_RELAXED, __HIP_MEMORY_SCOPE_AGENT);
        xm_r = xin_r + ((y0 + y1) + (y2 + y3));
        x = xm_r;
      }
      // LN2 -> z16
      float s1 = x, s2 = x * x;
#pragma unroll
      for (int o = 32; o >= 1; o >>= 1) { s1 += __shfl_xor(s1, o, 64); s2 += __shfl_xor(s2, o, 64); }
      if (tid < 256 && (tid & 63) == 0) { s_red[tid >> 6] = s1; s_red[8 + (tid >> 6)] = s2; }
      __syncthreads();
      if (tid < 256) {
        float S1 = s_red[0] + s_red[1] + s_red[2] + s_red[3];
        float S2 = s_red[8] + s_red[9] + s_red[10] + s_red[11];
        float m = S1 * (1.f / 256), rs = rsqrtf(S2 * (1.f / 256) - m * m + 1e-6f);
        float v = (x - m) * rs * p2s_r + p2b_r;
        float vn = __shfl_xor(v, 1);
        if (!(tid & 1)) s_z16[tid >> 1] = pack2(v, vn);
      }
    }
    __syncthreads();

    // FFN1 slice + gelu
    mvr<64, 4, 16, 256>(wW1, s_z16, s_part, tid);
    __syncthreads();
    if (tid < 256) {
      float v = 0.f;
#pragma unroll
      for (int s = 0; s < 8; ++s) v += s_part[s * 256 + tid];
      float gl = gelu_f(v + b1_r);
      float vn = __shfl_xor(gl, 1);
      if (!(tid & 1)) s_h16[tid >> 1] = pack2(gl, vn);
    }
    __syncthreads();

    // FFN2 slice: half regs, half LDS
    {
      const int g = tid & 63, s = tid >> 6;
      float acc[4] = {0.f, 0.f, 0.f, 0.f};
#pragma unroll
      for (int jj = 0; jj < 8; ++jj) {
        u32 xp = s_h16[s * 16 + jj];
        acc[0] = dot2(xp, wW2r[jj * 4 + 0], acc[0]);
        acc[1] = dot2(xp, wW2r[jj * 4 + 1], acc[1]);
        acc[2] = dot2(xp, wW2r[jj * 4 + 2], acc[2]);
        acc[3] = dot2(xp, wW2r[jj * 4 + 3], acc[3]);
      }
#pragma unroll
      for (int jj = 0; jj < 8; ++jj) {
        u32 xp = s_h16[s * 16 + 8 + jj];
        const u32* wp = &s_w2[(s * 8 + jj) * 256 + g * 4];
        acc[0] = dot2(xp, wp[0], acc[0]);
        acc[1] = dot2(xp, wp[1], acc[1]);
        acc[2] = dot2(xp, wp[2], acc[2]);
        acc[3] = dot2(xp, wp[3], acc[3]);
      }
      float* pp = s_part + s * 256 + g * 4;
      pp[0] = acc[0]; pp[1] = acc[1]; pp[2] = acc[2]; pp[3] = acc[3];
    }
    __syncthreads();
    if (tid < 256) {
      float v = 0.f;
#pragma unroll
      for (int s = 0; s < 8; ++s) v += s_part[s * 256 + tid];
      if (j == 0) v += xm_r + b2_r;
      __hip_atomic_store(&pxo[(b * 4 + j) * 256 + tid], v, __ATOMIC_RELAXED, __HIP_MEMORY_SCOPE_AGENT);
    }
    __syncthreads();
    if (tid == 0) {
      __threadfence();
      __hip_atomic_store(&seqx[b * 4 + j], t + 1, __ATOMIC_RELEASE, __HIP_MEMORY_SCOPE_AGENT);
    }
    if (tid < 4) {
      while (__hip_atomic_load(&seqx[b * 4 + tid], __ATOMIC_ACQUIRE, __HIP_MEMORY_SCOPE_AGENT) < t + 1)
        __builtin_amdgcn_s_sleep(1);
    }
    __syncthreads();
    if (tid < 256) {
      float x0 = __hip_atomic_load(&pxo[(b * 4 + 0) * 256 + tid], __ATOMIC_RELAXED, __HIP_MEMORY_SCOPE_AGENT);
      float x1 = __hip_atomic_load(&pxo[(b * 4 + 1) * 256 + tid], __ATOMIC_RELAXED, __HIP_MEMORY_SCOPE_AGENT);
      float x2 = __hip_atomic_load(&pxo[(b * 4 + 2) * 256 + tid], __ATOMIC_RELAXED, __HIP_MEMORY_SCOPE_AGENT);
      float x3 = __hip_atomic_load(&pxo[(b * 4 + 3) * 256 + tid], __ATOMIC_RELAXED, __HIP_MEMORY_SCOPE_AGENT);
      float xo = (x0 + x1) + (x2 + x3);
      const int frz = (s_frz[t >> 2] >> ((t & 3) * 8)) & 0xff;
      if (!frz) ssum_r = ssum_r * l_r + xo * (1.f - l_r);
      if (j == 0) {
        float vn = __shfl_xor(xo, 1);
        if (!(tid & 1)) xog[((size_t)b * TT + t) * 128 + (tid >> 1)] = pack2(xo, vn);
      }
    }
    __syncthreads();
  }
}

// logits = xout(32768x256 f16) @ Wa(256x1024 f16) + ba, fp32 out
__global__ __launch_bounds__(256) void logits_kernel(
    const u16* __restrict__ xo, const u16* __restrict__ Wa,
    const float* __restrict__ ba, float* __restrict__ out) {
  __shared__ float AsT[64][68];
  __shared__ float Bs[64][68];
  const int r0 = blockIdx.x * 64;
  const int c0 = blockIdx.y * 64;
  const int tid = threadIdx.x;
  const int tx = tid & 15, ty = tid >> 4;
  float acc[4][4] = {};
  for (int k0 = 0; k0 < EE; k0 += 64) {
    __syncthreads();
    for (int l = tid * 4; l < 4096; l += 1024) {
      int rr = l >> 6, cc = l & 63;
      us4 av = *(const us4*)(xo + ((size_t)(r0 + rr)) * EE + k0 + cc);
      us4 wv = *(const us4*)(Wa + ((size_t)(k0 + rr)) * 1024 + c0 + cc);
#pragma unroll
      for (int jj = 0; jj < 4; ++jj) {
        AsT[cc + jj][rr] = h2f((u16)av[jj]);
        Bs[rr][cc + jj] = h2f((u16)wv[jj]);
      }
    }
    __syncthreads();
#pragma unroll 4
    for (int kk = 0; kk < 64; ++kk) {
      float4 a4 = *(const float4*)&AsT[kk][ty * 4];
      float4 b4 = *(const float4*)&Bs[kk][tx * 4];
      float av_[4] = {a4.x, a4.y, a4.z, a4.w};
      float bv_[4] = {b4.x, b4.y, b4.z, b4.w};
#pragma unroll
      for (int i = 0; i < 4; ++i)
#pragma unroll
        for (int jj = 0; jj < 4; ++jj) acc[i][jj] += av_[i] * bv_[jj];
    }
  }
  float bav[4];
#pragma unroll
  for (int jj = 0; jj < 4; ++jj) bav[jj] = ba[c0 + tx * 4 + jj];
#pragma unroll
  for (int i = 0; i < 4; ++i) {
    float4 v;
    v.x = acc[i][0] + bav[0];
    v.y = acc[i][1] + bav[1];
    v.z = acc[i][2] + bav[2];
    v.w = acc[i][3] + bav[3];
    *(float4*)(out + ((size_t)(r0 + ty * 4 + i)) * 1024 + c0 + tx * 4) = v;
  }
}

extern "C" void kernel_launch(void* const* d_in, const int* in_sizes, int n_in,
                              void* d_out, int out_size, void* d_ws, size_t ws_size,
                              hipStream_t stream) {
  const float* obs  = (const float*)d_in[0];
  const unsigned char* freeze = (const unsigned char*)d_in[1];
  const float* Wi   = (const float*)d_in[2];
  const float* bi   = (const float*)d_in[3];
  const float* temb = (const float*)d_in[4];
  const float* alpha = (const float*)d_in[5];
  const float* lam  = (const float*)d_in[6];
  const float* ln1s = (const float*)d_in[7];
  const float* ln1b = (const float*)d_in[8];
  const float* Wq   = (const float*)d_in[9];
  const float* bq   = (const float*)d_in[10];
  const float* Wk   = (const float*)d_in[11];
  const float* bk   = (const float*)d_in[12];
  const float* Wv   = (const float*)d_in[13];
  const float* bv   = (const float*)d_in[14];
  const float* Wo   = (const float*)d_in[15];
  const float* bo   = (const float*)d_in[16];
  const float* ln2s = (const float*)d_in[17];
  const float* ln2b = (const float*)d_in[18];
  const float* W1   = (const float*)d_in[19];
  const float* b1   = (const float*)d_in[20];
  const float* W2   = (const float*)d_in[21];
  const float* b2   = (const float*)d_in[22];
  const float* Wa   = (const float*)d_in[23];
  const float* ba   = (const float*)d_in[24];
  u16* ws = (u16*)d_ws;

  hipLaunchKernelGGL(convert_kernel, dim3((CONV_TOTAL + 255) / 256), dim3(256), 0, stream,
                     Wi, Wq, Wk, Wv, Wo, W1, W2, Wa, ws);
  hipLaunchKernelGGL(scan_kernel, dim3(BB * 4), dim3(NT), 0, stream,
                     obs, freeze, bi, temb, alpha, lam, ln1s, ln1b,
                     bq, bk, bv, bo, ln2s, ln2b, b1, b2, ws);
  hipLaunchKernelGGL(logits_kernel, dim3(BB * TT / 64, 1024 / 64), dim3(256), 0, stream,
                     ws + 2 * W_XO, ws + 2 * W_WA, ba, (float*)d_out);
}